// Round 1
// baseline (755.991 us; speedup 1.0000x reference)
//
#include <hip/hip_runtime.h>

// Modern Hopfield retrieval, B=2048, N=100000, D=512, beta=8, steps=2.
// Candidate-filter architecture (unchanged):
// 1) i8 MFMA prepass over 8192 sampled cols -> per-row approx max m0.
// 2) i8 MFMA full gemm, epilogue collects candidate cols with logit > m0-35.
// 3) finalize: exact fp32 logits for candidates, survivors within 15 of max.
// THIS ROUND: gemm rebuilt as 256x256-tile / 8-wave / 3-buffer pipelined
// schedule: counted vmcnt (never 0 in main loop), raw s_barrier (1/K-step),
// XOR chunk swizzle for conflict-free ds_read_b128, setprio around MFMA.

#define B_ROWS 2048
#define DDIM   512
#define NTOT   100000
#define NPAD   100096          // 391*256
#define QB256  8               // 2048/256
#define NT256  391             // 100096/256
#define PT256  32              // prepass samples 8192 cols (any subset is safe)
#define CAP    2048            // candidate slots per row
#define SCAP   512             // survivor slots (typical 1-3)
#define MARGIN 35.0f           // 15 (weight cutoff) + 2*4sigma quant err bound
#define WCUT   15.0f           // survivor cutoff: weight >= e^-15

typedef int   i32x4 __attribute__((ext_vector_type(4)));

#define VMCNT(n) asm volatile("s_waitcnt vmcnt(" #n ")" ::: "memory")
#define LGK0()   asm volatile("s_waitcnt lgkmcnt(0)" ::: "memory")
#define BARR()   do { __builtin_amdgcn_s_barrier(); asm volatile("" ::: "memory"); } while(0)

__device__ inline unsigned encf(float f){                // order-preserving f32->u32
  unsigned u = __float_as_uint(f);
  return (u & 0x80000000u) ? ~u : (u | 0x80000000u);
}
__device__ inline float decf(unsigned u){
  unsigned v = (u & 0x80000000u) ? (u ^ 0x80000000u) : ~u;
  return __uint_as_float(v);
}
__device__ inline void llds16(const void* g, void* l){
  // async global->LDS, 16B/lane; LDS dest is wave-uniform base + lane*16
  __builtin_amdgcn_global_load_lds(
      (const __attribute__((address_space(1))) unsigned int*)(unsigned long long)g,
      (__attribute__((address_space(3))) unsigned int*)(unsigned long long)l,
      16, 0, 0);
}
__device__ inline unsigned q4(float a, float b, float c, float d, float mult){
  int qa = (int)fmaxf(-127.f, fminf(127.f, rintf(a*mult)));
  int qb = (int)fmaxf(-127.f, fminf(127.f, rintf(b*mult)));
  int qc = (int)fmaxf(-127.f, fminf(127.f, rintf(c*mult)));
  int qd = (int)fmaxf(-127.f, fminf(127.f, rintf(d*mult)));
  return (qa & 0xff) | ((qb & 0xff) << 8) | ((qc & 0xff) << 16) | ((qd & 0xff) << 24);
}

__global__ void cvt_i8(const float* __restrict__ src, signed char* __restrict__ dst,
                       long nsrc, long ndst, float mult){
  long i = ((long)blockIdx.x * blockDim.x + threadIdx.x) * 16;
  if (i >= ndst) return;
  uint4 o;
  if (i < nsrc){
    const float4* p = (const float4*)(src + i);
    float4 a = p[0], b = p[1], c = p[2], d = p[3];
    o.x = q4(a.x, a.y, a.z, a.w, mult);
    o.y = q4(b.x, b.y, b.z, b.w, mult);
    o.z = q4(c.x, c.y, c.z, c.w, mult);
    o.w = q4(d.x, d.y, d.z, d.w, mult);
  } else { o.x = o.y = o.z = o.w = 0u; }                 // zero pad rows >= NTOT
  *(uint4*)(dst + i) = o;
}

__global__ void init_stats(unsigned* __restrict__ m0u, unsigned* __restrict__ cnt){
  int i = blockIdx.x * blockDim.x + threadIdx.x;
  if (i < B_ROWS){ m0u[i] = 0u; cnt[i] = 0u; }           // 0 == encf(-huge)
}

// 256x256 tile, BK=64, 8 waves (2M x 4N, 128x64 per wave), 3-buffer pipeline.
// LDS buffer b (32 KB): A tile [256][64] at +0, B tile [256][64] at +16384.
// Swizzle: 16-B chunk of row r stored at chunk slot (c ^ ((r>>1)&3)) -- balanced
// across the 8 bank slots, conflict-free ds_read_b128. global_load_lds writes
// linearly, so the *global source* address carries the inverse swizzle.
// MODE 0: prepass (per-row max -> atomicMax m0u). MODE 1: collect candidates.
template<int MODE>
__launch_bounds__(512, 2)
__global__ void gemm_tile(const signed char* __restrict__ A,   // [2048][512] i8 (quant 8*x)
                          const signed char* __restrict__ Bm,  // [100096][512] i8 (quant M)
                          unsigned* __restrict__ m0u,
                          unsigned* __restrict__ cnt,
                          int* __restrict__ cand,
                          float dq){                           // dequant scale sA*sM
  extern __shared__ signed char smem[];                  // 3 * 32768 bytes
  __shared__ float tt[256];

  const int qblk = blockIdx.x, nblk = blockIdx.y;
  const int tid  = threadIdx.x;
  const int lane = tid & 63, wave = tid >> 6;
  const int wr = wave >> 2, wc = wave & 3;               // 2x4 waves, 128x64 each
  const int quad = lane >> 4, l15 = lane & 15;

  if (MODE == 1 && tid < 256) tt[tid] = decf(m0u[qblk*256 + tid]) - MARGIN;

  // ---- staging geometry (per lane; constant across K-tiles) ----
  // wave w stages rows w*16..w*16+15 of each 128-row half; lane covers
  // row = w*16 + lane/4, chunk slot p = lane&3. Source chunk = p ^ s(row),
  // s(row) = (row>>1)&3 = (lane>>3)&3  (w*8 and +128 drop out mod 4).
  const int srow = wave*16 + (lane >> 2);
  const int sc   = (lane & 3) ^ ((lane >> 3) & 3);
  const signed char* gA0 = A  + (size_t)(qblk*256 + srow)*DDIM + sc*16;
  const signed char* gA1 = gA0 + (size_t)128*DDIM;
  const signed char* gB0 = Bm + (size_t)(nblk*256 + srow)*DDIM + sc*16;
  const signed char* gB1 = gB0 + (size_t)128*DDIM;

  // ---- fragment read offsets (within a 32 KB buffer) ----
  // A frag i: row r = wr*128 + i*16 + l15, want chunk quad ->
  // read slot quad ^ s(r); s(r) = (l15>>1)&3 (wr*64, i*8 drop out mod 4).
  const int swz = (quad ^ ((l15 >> 1) & 3)) << 4;
  int offA[8], offB[4];
  #pragma unroll
  for (int i = 0; i < 8; i++) offA[i] = (wr*128 + i*16 + l15)*64 + swz;
  #pragma unroll
  for (int j = 0; j < 4; j++) offB[j] = 16384 + (wc*64 + j*16 + l15)*64 + swz;

  i32x4 acc[8][4] = {};

  auto STAGE = [&](int kb, int b){
    signed char* lb = smem + b*32768;
    const size_t o = (size_t)kb*64;
    llds16(gA0 + o, lb + wave*1024);
    llds16(gA1 + o, lb + 8192  + wave*1024);
    llds16(gB0 + o, lb + 16384 + wave*1024);
    llds16(gB1 + o, lb + 16384 + 8192 + wave*1024);
  };

  // Pipeline: buffers hold tiles {t, t+1, t+2 (in flight)}. One barrier per
  // K-step; vmcnt never drained in the main loop (4 loads per tile per wave).
  STAGE(0, 0); STAGE(1, 1);
  VMCNT(4); BARR();                                      // tile 0 landed everywhere

  #pragma unroll
  for (int t = 0; t < 8; ++t){                           // 512/64 = 8 K-tiles
    const int cb = t % 3;
    if (t + 2 < 8) STAGE(t + 2, (t + 2) % 3);            // target freed at t-1's barrier
    const signed char* bb = smem + cb*32768;
    i32x4 bf[4], af[8];
    #pragma unroll
    for (int j = 0; j < 4; j++) bf[j] = *(const i32x4*)(bb + offB[j]);
    #pragma unroll
    for (int i = 0; i < 8; i++) af[i] = *(const i32x4*)(bb + offA[i]);
    __builtin_amdgcn_s_setprio(1);
    #pragma unroll
    for (int i = 0; i < 8; i++)
      #pragma unroll
      for (int j = 0; j < 4; j++)
        acc[i][j] = __builtin_amdgcn_mfma_i32_16x16x64_i8(af[i], bf[j], acc[i][j], 0, 0, 0);
    __builtin_amdgcn_s_setprio(0);
    if (t < 7){
      LGK0();                                            // my reads of cb drained
      if (t < 6) { VMCNT(4); } else { VMCNT(0); }        // next tile landed (tail: drain)
      BARR();
    }
  }

  // C/D layout (shape-determined, m89/m121-verified): col = lane&15, row = quad*4 + reg
  if (MODE == 0){
    #pragma unroll
    for (int i = 0; i < 8; i++){
      #pragma unroll
      for (int r = 0; r < 4; r++){
        float v = fmaxf(fmaxf((float)acc[i][0][r], (float)acc[i][1][r]),
                        fmaxf((float)acc[i][2][r], (float)acc[i][3][r])) * dq;
        #pragma unroll
        for (int m = 1; m < 16; m <<= 1) v = fmaxf(v, __shfl_xor(v, m));
        if (l15 == 0){
          int row = qblk*256 + wr*128 + i*16 + quad*4 + r;
          atomicMax(&m0u[row], encf(v));
        }
      }
    }
  } else {
    const int nbase = nblk*256 + wc*64 + l15;
    #pragma unroll
    for (int i = 0; i < 8; i++){
      #pragma unroll
      for (int r = 0; r < 4; r++){
        const int lrow = wr*128 + i*16 + quad*4 + r;
        const float th = tt[lrow];
        #pragma unroll
        for (int j = 0; j < 4; j++){
          float v = (float)acc[i][j][r] * dq;
          int n = nbase + j*16;
          if (v > th && n < NTOT){                       // rare
            int q = qblk*256 + lrow;
            unsigned pos = atomicAdd(&cnt[q], 1u);
            if (pos < CAP) cand[(size_t)q*CAP + pos] = n;
          }
        }
      }
    }
  }
}

__global__ void finalize_row(const float* __restrict__ xin, const float* __restrict__ M,
                             const int* __restrict__ cand, const unsigned* __restrict__ cnt,
                             float* __restrict__ xout){
  __shared__ float xs[DDIM];
  __shared__ float lc[CAP];
  __shared__ int   sv[SCAP];
  __shared__ float mred[4];
  __shared__ int   ns;
  const int q = blockIdx.x, tid = threadIdx.x;
  const int wave = tid >> 6, lane = tid & 63;
  xs[tid]       = xin[(size_t)q*DDIM + tid];
  xs[tid + 256] = xin[(size_t)q*DDIM + 256 + tid];
  if (tid == 0) ns = 0;
  const unsigned cq = cnt[q];
  const int c0 = (int)(cq < (unsigned)CAP ? cq : (unsigned)CAP);
  __syncthreads();

  // Phase 1: exact fp32 logits for candidates (one wave per candidate)
  for (int c = wave; c < c0; c += 4){
    const float* Mr = M + (size_t)cand[(size_t)q*CAP + c]*DDIM;
    float s = 0.f;
    #pragma unroll
    for (int k = 0; k < 8; k++) s += xs[lane + 64*k] * Mr[lane + 64*k];
    #pragma unroll
    for (int o = 32; o; o >>= 1) s += __shfl_xor(s, o);
    if (lane == 0) lc[c] = 8.0f * s;
  }
  __syncthreads();

  // Phase 2: parallel max over candidates
  float m = -3.0e38f;
  for (int c = tid; c < c0; c += 256) m = fmaxf(m, lc[c]);
  #pragma unroll
  for (int o = 32; o; o >>= 1) m = fmaxf(m, __shfl_xor(m, o));
  if (lane == 0) mred[wave] = m;
  __syncthreads();
  m = fmaxf(fmaxf(mred[0], mred[1]), fmaxf(mred[2], mred[3]));

  // Phase 3: compact survivors (weight >= e^-WCUT; dropped tail < 7e-4 abs out)
  for (int c = tid; c < c0; c += 256){
    if (lc[c] > m - WCUT){
      int p = atomicAdd(&ns, 1);
      if (p < SCAP) sv[p] = c;
    }
  }
  __syncthreads();
  const int nsv = ns < SCAP ? ns : SCAP;

  // Phase 4: weighted gather over survivors only (typical 1-3)
  float Z = 0.f, a0 = 0.f, a1 = 0.f;
  for (int i = 0; i < nsv; i++){
    const int c = sv[i];
    const float w = expf(lc[c] - m);
    const float* Mr = M + (size_t)cand[(size_t)q*CAP + c]*DDIM;
    Z  += w;
    a0 += w * Mr[tid];
    a1 += w * Mr[tid + 256];
  }
  xout[(size_t)q*DDIM + tid]       = 1.f/(1.f + expf(-a0/Z));
  xout[(size_t)q*DDIM + tid + 256] = 1.f/(1.f + expf(-a1/Z));
}

extern "C" void kernel_launch(void* const* d_in, const int* in_sizes, int n_in,
                              void* d_out, int out_size, void* d_ws, size_t ws_size,
                              hipStream_t stream){
  const float* query = (const float*)d_in[0];
  const float* M     = (const float*)d_in[1];
  float* out = (float*)d_out;
  // steps (d_in[2]) is fixed at 2 for this problem; hardcoded below.

  char* w = (char*)d_ws;
  size_t off = 0;
  signed char* Bq   = (signed char*)(w + off); off += (size_t)NPAD*DDIM;     // 51.2 MB
  signed char* Aq   = (signed char*)(w + off); off += (size_t)B_ROWS*DDIM;   // 1 MB
  float*       xbuf = (float*)(w + off);       off += (size_t)B_ROWS*DDIM*4; // 4 MB
  unsigned*    m0u  = (unsigned*)(w + off);    off += (size_t)B_ROWS*4;
  unsigned*    cnt  = (unsigned*)(w + off);    off += (size_t)B_ROWS*4;
  int*         cand = (int*)(w + off);         off += (size_t)B_ROWS*CAP*4;  // 16.8 MB
  if (ws_size < off) return;

  // 96 KB dynamic LDS for the gemm (host-side attr; graph-capture-safe, idempotent)
  hipFuncSetAttribute((const void*)gemm_tile<0>,
                      hipFuncAttributeMaxDynamicSharedMemorySize, 3*32768);
  hipFuncSetAttribute((const void*)gemm_tile<1>,
                      hipFuncAttributeMaxDynamicSharedMemorySize, 3*32768);

  // M quant: clip 4 sigma (N(0,1) entries), step 4/127
  const float MCLIP = 4.0f;
  cvt_i8<<<(long)NPAD*DDIM/16/256, 256, 0, stream>>>(M, Bq, (long)NTOT*DDIM, (long)NPAD*DDIM,
                                                     127.0f/MCLIP);

  for (int step = 0; step < 2; ++step){
    const float* x = step ? (const float*)xbuf : query;
    float*       y = step ? out : xbuf;
    // A = 8*x quant: step0 x~N(0,1) -> clip |8x|<=40; step1 x=sigmoid in (0,1) -> |8x|<=8
    const float ACLIP = step ? 8.0f : 40.0f;
    const float multA = 8.0f * 127.0f / ACLIP;
    const float dq    = (ACLIP/127.0f) * (MCLIP/127.0f);
    init_stats<<<8, 256, 0, stream>>>(m0u, cnt);
    cvt_i8<<<(long)B_ROWS*DDIM/16/256, 256, 0, stream>>>(x, Aq, (long)B_ROWS*DDIM,
                                                         (long)B_ROWS*DDIM, multA);
    gemm_tile<0><<<dim3(QB256, PT256), 512, 3*32768, stream>>>(Aq, Bq, m0u, cnt, cand, dq);
    gemm_tile<1><<<dim3(QB256, NT256), 512, 3*32768, stream>>>(Aq, Bq, m0u, cnt, cand, dq);
    finalize_row<<<B_ROWS, 256, 0, stream>>>(x, M, cand, cnt, y);
  }
}

// Round 3
// 728.535 us; speedup vs baseline: 1.0377x; 1.0377x over previous
//
#include <hip/hip_runtime.h>

// Modern Hopfield retrieval, B=2048, N=100000, D=512, beta=8, steps=2.
// Candidate-filter architecture (unchanged):
// 1) i8 MFMA prepass over 8192 sampled cols -> per-row approx max m0.
// 2) i8 MFMA full gemm, epilogue collects candidate cols with logit > m0-35.
// 3) finalize: exact fp32 logits for candidates, survivors within 15 of max.
// R2 design (resubmit, hardened): m201-style phase schedule. Per K-tile,
// 4 quadrant phases {ds_read frags | 1 stage load | barrier | lgkmcnt(0) |
// sched_barrier(0) (rule #18 fence) | 8 MFMA | barrier}; 4 tile-buffers
// (128 KB), vmcnt(4) once per tile (never 0 in steady state); XCD-chunked
// 1-D grid so each XCD reuses its B slice in L2 across qblks.

#define B_ROWS 2048
#define DDIM   512
#define NTOT   100000
#define NPAD   100096          // 391*256
#define QB256  8               // 2048/256
#define NT256  391             // 100096/256
#define PT256  32              // prepass samples 8192 cols (any subset is safe)
#define CAP    2048            // candidate slots per row
#define SCAP   512             // survivor slots (typical 1-3)
#define MARGIN 35.0f           // 15 (weight cutoff) + 2*4sigma quant err bound
#define WCUT   15.0f           // survivor cutoff: weight >= e^-15

typedef int   i32x4 __attribute__((ext_vector_type(4)));

#define VMCNT(n) asm volatile("s_waitcnt vmcnt(" #n ")" ::: "memory")
#define LGK0()   asm volatile("s_waitcnt lgkmcnt(0)" ::: "memory")
#define SCHED0() __builtin_amdgcn_sched_barrier(0)
#define BARR()   do { __builtin_amdgcn_s_barrier(); asm volatile("" ::: "memory"); } while(0)

__device__ inline unsigned encf(float f){                // order-preserving f32->u32
  unsigned u = __float_as_uint(f);
  return (u & 0x80000000u) ? ~u : (u | 0x80000000u);
}
__device__ inline float decf(unsigned u){
  unsigned v = (u & 0x80000000u) ? (u ^ 0x80000000u) : ~u;
  return __uint_as_float(v);
}
__device__ inline void llds16(const void* g, void* l){
  // async global->LDS, 16B/lane; LDS dest is wave-uniform base + lane*16
  __builtin_amdgcn_global_load_lds(
      (const __attribute__((address_space(1))) unsigned int*)(unsigned long long)g,
      (__attribute__((address_space(3))) unsigned int*)(unsigned long long)l,
      16, 0, 0);
}
__device__ inline unsigned q4(float a, float b, float c, float d, float mult){
  int qa = (int)fmaxf(-127.f, fminf(127.f, rintf(a*mult)));
  int qb = (int)fmaxf(-127.f, fminf(127.f, rintf(b*mult)));
  int qc = (int)fmaxf(-127.f, fminf(127.f, rintf(c*mult)));
  int qd = (int)fmaxf(-127.f, fminf(127.f, rintf(d*mult)));
  return (qa & 0xff) | ((qb & 0xff) << 8) | ((qc & 0xff) << 16) | ((qd & 0xff) << 24);
}

__global__ void cvt_i8(const float* __restrict__ src, signed char* __restrict__ dst,
                       long nsrc, long ndst, float mult){
  long i = ((long)blockIdx.x * blockDim.x + threadIdx.x) * 16;
  if (i >= ndst) return;
  uint4 o;
  if (i < nsrc){
    const float4* p = (const float4*)(src + i);
    float4 a = p[0], b = p[1], c = p[2], d = p[3];
    o.x = q4(a.x, a.y, a.z, a.w, mult);
    o.y = q4(b.x, b.y, b.z, b.w, mult);
    o.z = q4(c.x, c.y, c.z, c.w, mult);
    o.w = q4(d.x, d.y, d.z, d.w, mult);
  } else { o.x = o.y = o.z = o.w = 0u; }                 // zero pad rows >= NTOT
  *(uint4*)(dst + i) = o;
}

__global__ void init_stats(unsigned* __restrict__ m0u, unsigned* __restrict__ cnt){
  int i = blockIdx.x * blockDim.x + threadIdx.x;
  if (i < B_ROWS){ m0u[i] = 0u; cnt[i] = 0u; }           // 0 == encf(-huge)
}

// 256x256 tile, BK=64, 8 waves (2M x 4N, 128x64 per wave), 4 tile-buffers.
// Per K-tile t: 4 quadrant phases. Quadrant q uses A-half (q>>1), B-half (q&1);
// halves are cached in regs so ds_reads/tile = 12 (A:8, B:4) not 24.
// Each phase stages exactly one unit of tile t+2 (4 units = full tile).
// vmcnt(4) at tile end: the 4 newest outstanding = tile t+2 => t+1 landed.
// Swizzle (verified R1, conflicts=0): chunk slot c of row r stored at
// c ^ ((r>>1)&3); global source carries the inverse (global_load_lds is linear).
// MODE 0: prepass (per-row max -> atomicMax m0u). MODE 1: collect candidates.
template<int MODE>
__launch_bounds__(512, 2)
__global__ void gemm_tile(const signed char* __restrict__ A,   // [2048][512] i8 (quant 8*x)
                          const signed char* __restrict__ Bm,  // [100096][512] i8 (quant M)
                          unsigned* __restrict__ m0u,
                          unsigned* __restrict__ cnt,
                          int* __restrict__ cand,
                          float dq,                            // dequant scale sA*sM
                          int nbt){                            // # n-tiles in grid
  extern __shared__ signed char smem[];                  // 4 * 32768 bytes
  __shared__ float tt[256];

  // XCD-chunked bijective swizzle (grid = 8*nbt, divisible by 8): XCD c
  // (= bid%8) owns contiguous work ids [c*nbt, (c+1)*nbt): a contiguous nblk
  // chunk with the 8 qblks of each nblk adjacent -> B tile L2-reused 8x.
  const int bid = blockIdx.x;
  const int w    = (bid & 7) * nbt + (bid >> 3);
  const int qblk = w & 7, nblk = w >> 3;

  const int tid  = threadIdx.x;
  const int lane = tid & 63, wave = tid >> 6;
  const int wr = wave >> 2, wc = wave & 3;               // 2x4 waves, 128x64 each
  const int quad = lane >> 4, l15 = lane & 15;

  // ---- staging geometry (per lane; constant across K-tiles) ----
  const int srow = wave*16 + (lane >> 2);
  const int sc   = (lane & 3) ^ ((lane >> 3) & 3);
  const signed char* gA0 = A  + (size_t)(qblk*256 + srow)*DDIM + sc*16;
  const signed char* gA1 = gA0 + (size_t)128*DDIM;
  const signed char* gB0 = Bm + (size_t)(nblk*256 + srow)*DDIM + sc*16;
  const signed char* gB1 = gB0 + (size_t)128*DDIM;

  // ---- fragment read offsets (within a 32 KB tile buffer) ----
  const int swz = (quad ^ ((l15 >> 1) & 3)) << 4;
  int offA[8], offB[4];
  #pragma unroll
  for (int i = 0; i < 8; i++) offA[i] = (wr*128 + i*16 + l15)*64 + swz;
  #pragma unroll
  for (int j = 0; j < 4; j++) offB[j] = 16384 + (wc*64 + j*16 + l15)*64 + swz;

  i32x4 acc[8][4] = {};
  i32x4 afA[4], afB[4], bfA[2], bfB[2];                  // cached halves

  auto SUNIT = [&](int t, int u){                        // one stage unit (1 load/wave)
    signed char* lb = smem + (t & 3) * 32768;
    const size_t o = (size_t)t * 64;
    if (u == 0) llds16(gA0 + o, lb +         wave*1024);
    if (u == 1) llds16(gA1 + o, lb +  8192 + wave*1024);
    if (u == 2) llds16(gB0 + o, lb + 16384 + wave*1024);
    if (u == 3) llds16(gB1 + o, lb + 24576 + wave*1024);
  };

  // ---- prologue: stage tiles 0,1; wait tile 0; sync ----
  #pragma unroll
  for (int u = 0; u < 4; ++u) SUNIT(0, u);
  #pragma unroll
  for (int u = 0; u < 4; ++u) SUNIT(1, u);
  if (MODE == 1 && tid < 256) tt[tid] = decf(m0u[qblk*256 + tid]) - MARGIN;
  VMCNT(4); BARR();

  #pragma unroll
  for (int t = 0; t < 8; ++t){                           // 512/64 = 8 K-tiles
    const signed char* bb = smem + (t & 3) * 32768;
    // ---------- phase q0: read A-lo + B-lo, MFMA quadrant (A-lo x B-lo) ----
    #pragma unroll
    for (int i = 0; i < 4; i++) afA[i] = *(const i32x4*)(bb + offA[i]);
    bfA[0] = *(const i32x4*)(bb + offB[0]);
    bfA[1] = *(const i32x4*)(bb + offB[1]);
    if (t + 2 < 8) SUNIT(t + 2, 0);
    BARR(); LGK0(); SCHED0();
    __builtin_amdgcn_s_setprio(1);
    #pragma unroll
    for (int i = 0; i < 4; i++)
      #pragma unroll
      for (int j = 0; j < 2; j++)
        acc[i][j] = __builtin_amdgcn_mfma_i32_16x16x64_i8(afA[i], bfA[j], acc[i][j], 0, 0, 0);
    __builtin_amdgcn_s_setprio(0);
    BARR();
    // ---------- phase q1: read B-hi, MFMA (A-lo x B-hi) ----
    bfB[0] = *(const i32x4*)(bb + offB[2]);
    bfB[1] = *(const i32x4*)(bb + offB[3]);
    if (t + 2 < 8) SUNIT(t + 2, 1);
    BARR(); LGK0(); SCHED0();
    __builtin_amdgcn_s_setprio(1);
    #pragma unroll
    for (int i = 0; i < 4; i++)
      #pragma unroll
      for (int j = 0; j < 2; j++)
        acc[i][2+j] = __builtin_amdgcn_mfma_i32_16x16x64_i8(afA[i], bfB[j], acc[i][2+j], 0, 0, 0);
    __builtin_amdgcn_s_setprio(0);
    BARR();
    // ---------- phase q2: read A-hi, MFMA (A-hi x B-lo) ----
    #pragma unroll
    for (int i = 0; i < 4; i++) afB[i] = *(const i32x4*)(bb + offA[4+i]);
    if (t + 2 < 8) SUNIT(t + 2, 2);
    BARR(); LGK0(); SCHED0();
    __builtin_amdgcn_s_setprio(1);
    #pragma unroll
    for (int i = 0; i < 4; i++)
      #pragma unroll
      for (int j = 0; j < 2; j++)
        acc[4+i][j] = __builtin_amdgcn_mfma_i32_16x16x64_i8(afB[i], bfA[j], acc[4+i][j], 0, 0, 0);
    __builtin_amdgcn_s_setprio(0);
    BARR();
    // ---------- phase q3: no reads, MFMA (A-hi x B-hi); tile-end vmcnt ----
    if (t + 2 < 8) SUNIT(t + 2, 3);
    BARR(); LGK0(); SCHED0();
    __builtin_amdgcn_s_setprio(1);
    #pragma unroll
    for (int i = 0; i < 4; i++)
      #pragma unroll
      for (int j = 0; j < 2; j++)
        acc[4+i][2+j] = __builtin_amdgcn_mfma_i32_16x16x64_i8(afB[i], bfB[j], acc[4+i][2+j], 0, 0, 0);
    __builtin_amdgcn_s_setprio(0);
    if (t < 7){
      if (t < 6) { VMCNT(4); } else { VMCNT(0); }        // t+1 landed (tail: drain)
    }
    BARR();
  }

  // C/D layout (shape-determined, m89/m121-verified): col = lane&15, row = quad*4 + reg
  if (MODE == 0){
    #pragma unroll
    for (int i = 0; i < 8; i++){
      #pragma unroll
      for (int r = 0; r < 4; r++){
        float v = fmaxf(fmaxf((float)acc[i][0][r], (float)acc[i][1][r]),
                        fmaxf((float)acc[i][2][r], (float)acc[i][3][r])) * dq;
        #pragma unroll
        for (int m = 1; m < 16; m <<= 1) v = fmaxf(v, __shfl_xor(v, m));
        if (l15 == 0){
          int row = qblk*256 + wr*128 + i*16 + quad*4 + r;
          atomicMax(&m0u[row], encf(v));
        }
      }
    }
  } else {
    const int nbase = nblk*256 + wc*64 + l15;
    #pragma unroll
    for (int i = 0; i < 8; i++){
      #pragma unroll
      for (int r = 0; r < 4; r++){
        const int lrow = wr*128 + i*16 + quad*4 + r;
        const float th = tt[lrow];
        #pragma unroll
        for (int j = 0; j < 4; j++){
          float v = (float)acc[i][j][r] * dq;
          int n = nbase + j*16;
          if (v > th && n < NTOT){                       // rare
            int q = qblk*256 + lrow;
            unsigned pos = atomicAdd(&cnt[q], 1u);
            if (pos < CAP) cand[(size_t)q*CAP + pos] = n;
          }
        }
      }
    }
  }
}

__global__ void finalize_row(const float* __restrict__ xin, const float* __restrict__ M,
                             const int* __restrict__ cand, const unsigned* __restrict__ cnt,
                             float* __restrict__ xout){
  __shared__ float xs[DDIM];
  __shared__ float lc[CAP];
  __shared__ int   sv[SCAP];
  __shared__ float mred[4];
  __shared__ int   ns;
  const int q = blockIdx.x, tid = threadIdx.x;
  const int wave = tid >> 6, lane = tid & 63;
  xs[tid]       = xin[(size_t)q*DDIM + tid];
  xs[tid + 256] = xin[(size_t)q*DDIM + 256 + tid];
  if (tid == 0) ns = 0;
  const unsigned cq = cnt[q];
  const int c0 = (int)(cq < (unsigned)CAP ? cq : (unsigned)CAP);
  __syncthreads();

  // Phase 1: exact fp32 logits for candidates (one wave per candidate)
  for (int c = wave; c < c0; c += 4){
    const float* Mr = M + (size_t)cand[(size_t)q*CAP + c]*DDIM;
    float s = 0.f;
    #pragma unroll
    for (int k = 0; k < 8; k++) s += xs[lane + 64*k] * Mr[lane + 64*k];
    #pragma unroll
    for (int o = 32; o; o >>= 1) s += __shfl_xor(s, o);
    if (lane == 0) lc[c] = 8.0f * s;
  }
  __syncthreads();

  // Phase 2: parallel max over candidates
  float m = -3.0e38f;
  for (int c = tid; c < c0; c += 256) m = fmaxf(m, lc[c]);
  #pragma unroll
  for (int o = 32; o; o >>= 1) m = fmaxf(m, __shfl_xor(m, o));
  if (lane == 0) mred[wave] = m;
  __syncthreads();
  m = fmaxf(fmaxf(mred[0], mred[1]), fmaxf(mred[2], mred[3]));

  // Phase 3: compact survivors (weight >= e^-WCUT; dropped tail < 7e-4 abs out)
  for (int c = tid; c < c0; c += 256){
    if (lc[c] > m - WCUT){
      int p = atomicAdd(&ns, 1);
      if (p < SCAP) sv[p] = c;
    }
  }
  __syncthreads();
  const int nsv = ns < SCAP ? ns : SCAP;

  // Phase 4: weighted gather over survivors only (typical 1-3)
  float Z = 0.f, a0 = 0.f, a1 = 0.f;
  for (int i = 0; i < nsv; i++){
    const int c = sv[i];
    const float w = expf(lc[c] - m);
    const float* Mr = M + (size_t)cand[(size_t)q*CAP + c]*DDIM;
    Z  += w;
    a0 += w * Mr[tid];
    a1 += w * Mr[tid + 256];
  }
  xout[(size_t)q*DDIM + tid]       = 1.f/(1.f + expf(-a0/Z));
  xout[(size_t)q*DDIM + tid + 256] = 1.f/(1.f + expf(-a1/Z));
}

extern "C" void kernel_launch(void* const* d_in, const int* in_sizes, int n_in,
                              void* d_out, int out_size, void* d_ws, size_t ws_size,
                              hipStream_t stream){
  const float* query = (const float*)d_in[0];
  const float* M     = (const float*)d_in[1];
  float* out = (float*)d_out;
  // steps (d_in[2]) is fixed at 2 for this problem; hardcoded below.

  char* w = (char*)d_ws;
  size_t off = 0;
  signed char* Bq   = (signed char*)(w + off); off += (size_t)NPAD*DDIM;     // 51.2 MB
  signed char* Aq   = (signed char*)(w + off); off += (size_t)B_ROWS*DDIM;   // 1 MB
  float*       xbuf = (float*)(w + off);       off += (size_t)B_ROWS*DDIM*4; // 4 MB
  unsigned*    m0u  = (unsigned*)(w + off);    off += (size_t)B_ROWS*4;
  unsigned*    cnt  = (unsigned*)(w + off);    off += (size_t)B_ROWS*4;
  int*         cand = (int*)(w + off);         off += (size_t)B_ROWS*CAP*4;  // 16.8 MB
  if (ws_size < off) return;

  // 128 KB dynamic LDS for the gemm (host-side attr; graph-capture-safe, idempotent)
  hipFuncSetAttribute((const void*)gemm_tile<0>,
                      hipFuncAttributeMaxDynamicSharedMemorySize, 4*32768);
  hipFuncSetAttribute((const void*)gemm_tile<1>,
                      hipFuncAttributeMaxDynamicSharedMemorySize, 4*32768);

  // M quant: clip 4 sigma (N(0,1) entries), step 4/127
  const float MCLIP = 4.0f;
  cvt_i8<<<(long)NPAD*DDIM/16/256, 256, 0, stream>>>(M, Bq, (long)NTOT*DDIM, (long)NPAD*DDIM,
                                                     127.0f/MCLIP);

  for (int step = 0; step < 2; ++step){
    const float* x = step ? (const float*)xbuf : query;
    float*       y = step ? out : xbuf;
    // A = 8*x quant: step0 x~N(0,1) -> clip |8x|<=40; step1 x=sigmoid in (0,1) -> |8x|<=8
    const float ACLIP = step ? 8.0f : 40.0f;
    const float multA = 8.0f * 127.0f / ACLIP;
    const float dq    = (ACLIP/127.0f) * (MCLIP/127.0f);
    init_stats<<<8, 256, 0, stream>>>(m0u, cnt);
    cvt_i8<<<(long)B_ROWS*DDIM/16/256, 256, 0, stream>>>(x, Aq, (long)B_ROWS*DDIM,
                                                         (long)B_ROWS*DDIM, multA);
    gemm_tile<0><<<8*PT256, 512, 4*32768, stream>>>(Aq, Bq, m0u, cnt, cand, dq, PT256);
    gemm_tile<1><<<8*NT256, 512, 4*32768, stream>>>(Aq, Bq, m0u, cnt, cand, dq, NT256);
    finalize_row<<<B_ROWS, 256, 0, stream>>>(x, M, cand, cnt, y);
  }
}

// Round 4
// 653.612 us; speedup vs baseline: 1.1566x; 1.1146x over previous
//
#include <hip/hip_runtime.h>

// Modern Hopfield retrieval, B=2048, N=100000, D=512, beta=8, steps=2.
// Candidate-filter architecture (unchanged):
// 1) i8 MFMA prepass over 4096 sampled cols -> per-row approx max m0.
// 2) i8 MFMA full gemm, epilogue collects candidate cols with logit > m0-35.
// 3) finalize: exact fp32 logits for candidates, survivors within 15 of max.
// R4 gemm: 128^2 tile / 4 waves / 256 thr -> 3 INDEPENDENT blocks per CU
// (cross-block barrier stagger = the R0 mechanism that beat both single-block
// 256^2 schedules), keeping the R1-R3 verified mechanics: conflict-free XOR
// chunk swizzle (measured 0 conflicts), XCD-chunked grid (FETCH 200->30 MB),
// 3-buffer pipeline with counted vmcnt(4) (never 0 until tail), one raw
// barrier per K-tile (no full __syncthreads drain).

#define B_ROWS 2048
#define DDIM   512
#define NTOT   100000
#define NPAD   100096          // 782*128
#define QB128  16              // 2048/128
#define NT128  782             // 100096/128
#define PT128  32              // prepass samples 4096 cols (any subset is safe)
#define CAP    2048            // candidate slots per row
#define SCAP   512             // survivor slots (typical 1-3)
#define MARGIN 35.0f           // 15 (weight cutoff) + 2*4sigma quant err bound
#define WCUT   15.0f           // survivor cutoff: weight >= e^-15

typedef int   i32x4 __attribute__((ext_vector_type(4)));

#define VMCNT(n) asm volatile("s_waitcnt vmcnt(" #n ")" ::: "memory")
#define BARR()   do { __builtin_amdgcn_s_barrier(); asm volatile("" ::: "memory"); } while(0)

__device__ inline unsigned encf(float f){                // order-preserving f32->u32
  unsigned u = __float_as_uint(f);
  return (u & 0x80000000u) ? ~u : (u | 0x80000000u);
}
__device__ inline float decf(unsigned u){
  unsigned v = (u & 0x80000000u) ? (u ^ 0x80000000u) : ~u;
  return __uint_as_float(v);
}
__device__ inline void llds16(const void* g, void* l){
  // async global->LDS, 16B/lane; LDS dest is wave-uniform base + lane*16
  __builtin_amdgcn_global_load_lds(
      (const __attribute__((address_space(1))) unsigned int*)(unsigned long long)g,
      (__attribute__((address_space(3))) unsigned int*)(unsigned long long)l,
      16, 0, 0);
}
__device__ inline unsigned q4(float a, float b, float c, float d, float mult){
  int qa = (int)fmaxf(-127.f, fminf(127.f, rintf(a*mult)));
  int qb = (int)fmaxf(-127.f, fminf(127.f, rintf(b*mult)));
  int qc = (int)fmaxf(-127.f, fminf(127.f, rintf(c*mult)));
  int qd = (int)fmaxf(-127.f, fminf(127.f, rintf(d*mult)));
  return (qa & 0xff) | ((qb & 0xff) << 8) | ((qc & 0xff) << 16) | ((qd & 0xff) << 24);
}

__global__ void cvt_i8(const float* __restrict__ src, signed char* __restrict__ dst,
                       long nsrc, long ndst, float mult){
  long i = ((long)blockIdx.x * blockDim.x + threadIdx.x) * 16;
  if (i >= ndst) return;
  uint4 o;
  if (i < nsrc){
    const float4* p = (const float4*)(src + i);
    float4 a = p[0], b = p[1], c = p[2], d = p[3];
    o.x = q4(a.x, a.y, a.z, a.w, mult);
    o.y = q4(b.x, b.y, b.z, b.w, mult);
    o.z = q4(c.x, c.y, c.z, c.w, mult);
    o.w = q4(d.x, d.y, d.z, d.w, mult);
  } else { o.x = o.y = o.z = o.w = 0u; }                 // zero pad rows >= NTOT
  *(uint4*)(dst + i) = o;
}

__global__ void init_stats(unsigned* __restrict__ m0u, unsigned* __restrict__ cnt){
  int i = blockIdx.x * blockDim.x + threadIdx.x;
  if (i < B_ROWS){ m0u[i] = 0u; cnt[i] = 0u; }           // 0 == encf(-huge)
}

// 128x128 tile, BK=64, 4 waves (2x2, 64x64 each), 3 tile-buffers (48 KB).
// Per K-tile t: STAGE(t+2) first, 8 ds_read_b128 (plain C++ -> compiler's own
// fine lgkmcnt), 16 MFMA, then {vmcnt(4) counted; s_barrier} once per tile.
// 3-buffer hazards: tile t+2 overwrites buf((t-1)%3) -- all reads of t-1
// completed before each wave passed the end-of-(t-1) barrier (MFMA register
// deps force the lgkm wait); per-wave vmcnt(4)+barrier at end of t-1 ensures
// ALL waves' tile-t loads landed before any wave reads tile t.
// Swizzle (R1-verified, conflicts=0): chunk slot c of row r stored at
// c ^ ((r>>1)&3); global source carries the inverse (global_load_lds is linear).
// MODE 0: prepass (per-row max -> atomicMax m0u). MODE 1: collect candidates.
template<int MODE>
__launch_bounds__(256, 3)
__global__ void gemm_tile(const signed char* __restrict__ A,   // [2048][512] i8 (quant 8*x)
                          const signed char* __restrict__ Bm,  // [100096][512] i8 (quant M)
                          unsigned* __restrict__ m0u,
                          unsigned* __restrict__ cnt,
                          int* __restrict__ cand,
                          float dq,                            // dequant scale sA*sM
                          int cpx){                            // grid chunk per XCD
  extern __shared__ signed char smem[];                  // 3 * 16384 bytes
  __shared__ float tt[128];

  // XCD-chunked bijective swizzle (grid = 8*cpx): XCD c (= bid%8) owns work
  // ids [c*cpx, (c+1)*cpx). qblk cycles fastest -> each B tile (nblk) is
  // consumed by 16 near-concurrent blocks on the same XCD -> L2-reused 16x.
  const int bid = blockIdx.x;
  const int w    = (bid & 7) * cpx + (bid >> 3);
  const int qblk = w & 15, nblk = w >> 4;

  const int tid  = threadIdx.x;
  const int lane = tid & 63, wave = tid >> 6;
  const int wr = wave >> 1, wc = wave & 1;               // 2x2 waves, 64x64 each
  const int quad = lane >> 4, l15 = lane & 15;

  if (MODE == 1 && tid < 128) tt[tid] = decf(m0u[qblk*128 + tid]) - MARGIN;

  // ---- staging geometry (per lane; constant across K-tiles) ----
  // wave w stages rows w*16..w*16+15 of each 64-row half; lane covers
  // row = w*16 + lane/4, chunk slot p = lane&3, source chunk p ^ ((row>>1)&3)
  // = p ^ ((lane>>3)&3)  (w*8 drops out mod 4).
  const int srow = wave*16 + (lane >> 2);
  const int sc   = (lane & 3) ^ ((lane >> 3) & 3);
  const signed char* gA0 = A  + (size_t)(qblk*128 + srow)*DDIM + sc*16;
  const signed char* gA1 = gA0 + (size_t)64*DDIM;
  const signed char* gB0 = Bm + (size_t)(nblk*128 + srow)*DDIM + sc*16;
  const signed char* gB1 = gB0 + (size_t)64*DDIM;

  // ---- fragment read offsets (within a 16 KB tile buffer: A @0, B @8192) ----
  // frag row r = wr*64 + i*16 + l15 -> read slot quad ^ ((r>>1)&3) =
  // quad ^ ((l15>>1)&3)  (wr*32, i*8 drop out mod 4).
  const int swz = (quad ^ ((l15 >> 1) & 3)) << 4;
  int offA[4], offB[4];
  #pragma unroll
  for (int i = 0; i < 4; i++) offA[i] = (wr*64 + i*16 + l15)*64 + swz;
  #pragma unroll
  for (int j = 0; j < 4; j++) offB[j] = 8192 + (wc*64 + j*16 + l15)*64 + swz;

  i32x4 acc[4][4] = {};

  auto STAGE = [&](int t){                               // 4 llds16 per wave
    signed char* lb = smem + (t % 3) * 16384;
    const size_t o = (size_t)t * 64;
    llds16(gA0 + o, lb +         wave*1024);
    llds16(gA1 + o, lb +  4096 + wave*1024);
    llds16(gB0 + o, lb +  8192 + wave*1024);
    llds16(gB1 + o, lb + 12288 + wave*1024);
  };

  // ---- prologue: stage tiles 0,1; wait tile 0 (4 newest = tile 1); sync ----
  STAGE(0); STAGE(1);
  VMCNT(4); BARR();

  #pragma unroll
  for (int t = 0; t < 8; ++t){                           // 512/64 = 8 K-tiles
    const signed char* bb = smem + (t % 3) * 16384;
    if (t + 2 < 8) STAGE(t + 2);                         // issue before compute
    i32x4 af[4], bf[4];
    #pragma unroll
    for (int j = 0; j < 4; j++) bf[j] = *(const i32x4*)(bb + offB[j]);
    #pragma unroll
    for (int i = 0; i < 4; i++) af[i] = *(const i32x4*)(bb + offA[i]);
    __builtin_amdgcn_s_setprio(1);
    #pragma unroll
    for (int i = 0; i < 4; i++)
      #pragma unroll
      for (int j = 0; j < 4; j++)
        acc[i][j] = __builtin_amdgcn_mfma_i32_16x16x64_i8(af[i], bf[j], acc[i][j], 0, 0, 0);
    __builtin_amdgcn_s_setprio(0);
    if (t < 7){
      if (t < 6) { VMCNT(4); } else { VMCNT(0); }        // t+1 landed (tail: drain)
      BARR();
    }
  }

  // C/D layout (shape-determined, m89/m121-verified): col = lane&15, row = quad*4 + reg
  if (MODE == 0){
    #pragma unroll
    for (int i = 0; i < 4; i++){
      #pragma unroll
      for (int r = 0; r < 4; r++){
        float v = fmaxf(fmaxf((float)acc[i][0][r], (float)acc[i][1][r]),
                        fmaxf((float)acc[i][2][r], (float)acc[i][3][r])) * dq;
        #pragma unroll
        for (int m = 1; m < 16; m <<= 1) v = fmaxf(v, __shfl_xor(v, m));
        if (l15 == 0){
          int row = qblk*128 + wr*64 + i*16 + quad*4 + r;
          atomicMax(&m0u[row], encf(v));
        }
      }
    }
  } else {
    const int nbase = nblk*128 + wc*64 + l15;
    #pragma unroll
    for (int i = 0; i < 4; i++){
      #pragma unroll
      for (int r = 0; r < 4; r++){
        const int lrow = wr*64 + i*16 + quad*4 + r;
        const float th = tt[lrow];
        #pragma unroll
        for (int j = 0; j < 4; j++){
          float v = (float)acc[i][j][r] * dq;
          int n = nbase + j*16;
          if (v > th && n < NTOT){                       // rare
            int q = qblk*128 + lrow;
            unsigned pos = atomicAdd(&cnt[q], 1u);
            if (pos < CAP) cand[(size_t)q*CAP + pos] = n;
          }
        }
      }
    }
  }
}

__global__ void finalize_row(const float* __restrict__ xin, const float* __restrict__ M,
                             const int* __restrict__ cand, const unsigned* __restrict__ cnt,
                             float* __restrict__ xout){
  __shared__ float xs[DDIM];
  __shared__ float lc[CAP];
  __shared__ int   sv[SCAP];
  __shared__ float mred[4];
  __shared__ int   ns;
  const int q = blockIdx.x, tid = threadIdx.x;
  const int wave = tid >> 6, lane = tid & 63;
  xs[tid]       = xin[(size_t)q*DDIM + tid];
  xs[tid + 256] = xin[(size_t)q*DDIM + 256 + tid];
  if (tid == 0) ns = 0;
  const unsigned cq = cnt[q];
  const int c0 = (int)(cq < (unsigned)CAP ? cq : (unsigned)CAP);
  __syncthreads();

  // Phase 1: exact fp32 logits for candidates (one wave per candidate)
  for (int c = wave; c < c0; c += 4){
    const float* Mr = M + (size_t)cand[(size_t)q*CAP + c]*DDIM;
    float s = 0.f;
    #pragma unroll
    for (int k = 0; k < 8; k++) s += xs[lane + 64*k] * Mr[lane + 64*k];
    #pragma unroll
    for (int o = 32; o; o >>= 1) s += __shfl_xor(s, o);
    if (lane == 0) lc[c] = 8.0f * s;
  }
  __syncthreads();

  // Phase 2: parallel max over candidates
  float m = -3.0e38f;
  for (int c = tid; c < c0; c += 256) m = fmaxf(m, lc[c]);
  #pragma unroll
  for (int o = 32; o; o >>= 1) m = fmaxf(m, __shfl_xor(m, o));
  if (lane == 0) mred[wave] = m;
  __syncthreads();
  m = fmaxf(fmaxf(mred[0], mred[1]), fmaxf(mred[2], mred[3]));

  // Phase 3: compact survivors (weight >= e^-WCUT; dropped tail < 7e-4 abs out)
  for (int c = tid; c < c0; c += 256){
    if (lc[c] > m - WCUT){
      int p = atomicAdd(&ns, 1);
      if (p < SCAP) sv[p] = c;
    }
  }
  __syncthreads();
  const int nsv = ns < SCAP ? ns : SCAP;

  // Phase 4: weighted gather over survivors only (typical 1-3)
  float Z = 0.f, a0 = 0.f, a1 = 0.f;
  for (int i = 0; i < nsv; i++){
    const int c = sv[i];
    const float w = expf(lc[c] - m);
    const float* Mr = M + (size_t)cand[(size_t)q*CAP + c]*DDIM;
    Z  += w;
    a0 += w * Mr[tid];
    a1 += w * Mr[tid + 256];
  }
  xout[(size_t)q*DDIM + tid]       = 1.f/(1.f + expf(-a0/Z));
  xout[(size_t)q*DDIM + tid + 256] = 1.f/(1.f + expf(-a1/Z));
}

extern "C" void kernel_launch(void* const* d_in, const int* in_sizes, int n_in,
                              void* d_out, int out_size, void* d_ws, size_t ws_size,
                              hipStream_t stream){
  const float* query = (const float*)d_in[0];
  const float* M     = (const float*)d_in[1];
  float* out = (float*)d_out;
  // steps (d_in[2]) is fixed at 2 for this problem; hardcoded below.

  char* w = (char*)d_ws;
  size_t off = 0;
  signed char* Bq   = (signed char*)(w + off); off += (size_t)NPAD*DDIM;     // 51.2 MB
  signed char* Aq   = (signed char*)(w + off); off += (size_t)B_ROWS*DDIM;   // 1 MB
  float*       xbuf = (float*)(w + off);       off += (size_t)B_ROWS*DDIM*4; // 4 MB
  unsigned*    m0u  = (unsigned*)(w + off);    off += (size_t)B_ROWS*4;
  unsigned*    cnt  = (unsigned*)(w + off);    off += (size_t)B_ROWS*4;
  int*         cand = (int*)(w + off);         off += (size_t)B_ROWS*CAP*4;  // 16.8 MB
  if (ws_size < off) return;

  // dynamic LDS 48 KB (host-side attr; graph-capture-safe, idempotent)
  hipFuncSetAttribute((const void*)gemm_tile<0>,
                      hipFuncAttributeMaxDynamicSharedMemorySize, 3*16384);
  hipFuncSetAttribute((const void*)gemm_tile<1>,
                      hipFuncAttributeMaxDynamicSharedMemorySize, 3*16384);

  // M quant: clip 4 sigma (N(0,1) entries), step 4/127
  const float MCLIP = 4.0f;
  cvt_i8<<<(long)NPAD*DDIM/16/256, 256, 0, stream>>>(M, Bq, (long)NTOT*DDIM, (long)NPAD*DDIM,
                                                     127.0f/MCLIP);

  for (int step = 0; step < 2; ++step){
    const float* x = step ? (const float*)xbuf : query;
    float*       y = step ? out : xbuf;
    // A = 8*x quant: step0 x~N(0,1) -> clip |8x|<=40; step1 x=sigmoid in (0,1) -> |8x|<=8
    const float ACLIP = step ? 8.0f : 40.0f;
    const float multA = 8.0f * 127.0f / ACLIP;
    const float dq    = (ACLIP/127.0f) * (MCLIP/127.0f);
    init_stats<<<8, 256, 0, stream>>>(m0u, cnt);
    cvt_i8<<<(long)B_ROWS*DDIM/16/256, 256, 0, stream>>>(x, Aq, (long)B_ROWS*DDIM,
                                                         (long)B_ROWS*DDIM, multA);
    gemm_tile<0><<<16*PT128, 256, 3*16384, stream>>>(Aq, Bq, m0u, cnt, cand, dq, 16*PT128/8);
    gemm_tile<1><<<16*NT128, 256, 3*16384, stream>>>(Aq, Bq, m0u, cnt, cand, dq, 16*NT128/8);
    finalize_row<<<B_ROWS, 256, 0, stream>>>(x, M, cand, cnt, y);
  }
}

// Round 5
// 633.149 us; speedup vs baseline: 1.1940x; 1.0323x over previous
//
#include <hip/hip_runtime.h>

// Modern Hopfield retrieval, B=2048, N=100000, D=512, beta=8, steps=2.
// Candidate-filter architecture (unchanged):
// 1) i8 MFMA prepass over 4096 sampled cols -> per-row approx max m0.
// 2) i8 MFMA full gemm, epilogue collects candidate cols with logit > m0-35.
// 3) finalize: exact fp32 logits for candidates, survivors within 15 of max.
// R5 gemm: BM=256 x BN=128, 8 waves (4Mx2N, 64x64 each), 3 buffers x 24 KB
// -> 2 blocks/CU = 16 waves/CU. Rationale (R4 counters): staged L2 bytes per
// tile-period were ~90% of the per-CU L2 share vs MFMA cycles; BM=256 keeps
// staged bytes constant (48 KB/CU/tile) while raising MFMA work 1.33x ->
// L2 pressure 67% of share. Keeps verified mechanics: conflict-free XOR
// swizzle (0 conflicts), XCD-chunked grid (FETCH 200->30 MB), counted
// vmcnt(3) (never 0 until tail), one raw barrier per K-tile, setprio.
// init_stats folded into the A-quant cvt kernel (m0u/cnt ws-adjacent).

#define B_ROWS 2048
#define DDIM   512
#define NTOT   100000
#define NPAD   100096          // 782*128
#define QB     8               // 2048/256
#define NB     782             // 100096/128
#define PT     32              // prepass samples 4096 cols (any subset is safe)
#define CAP    2048            // candidate slots per row
#define SCAP   512             // survivor slots (typical 1-3)
#define MARGIN 35.0f           // 15 (weight cutoff) + 2*4sigma quant err bound
#define WCUT   15.0f           // survivor cutoff: weight >= e^-15

typedef int   i32x4 __attribute__((ext_vector_type(4)));

#define VMCNT(n) asm volatile("s_waitcnt vmcnt(" #n ")" ::: "memory")
#define BARR()   do { __builtin_amdgcn_s_barrier(); asm volatile("" ::: "memory"); } while(0)

__device__ inline unsigned encf(float f){                // order-preserving f32->u32
  unsigned u = __float_as_uint(f);
  return (u & 0x80000000u) ? ~u : (u | 0x80000000u);
}
__device__ inline float decf(unsigned u){
  unsigned v = (u & 0x80000000u) ? (u ^ 0x80000000u) : ~u;
  return __uint_as_float(v);
}
__device__ inline void llds16(const void* g, void* l){
  // async global->LDS, 16B/lane; LDS dest is wave-uniform base + lane*16
  __builtin_amdgcn_global_load_lds(
      (const __attribute__((address_space(1))) unsigned int*)(unsigned long long)g,
      (__attribute__((address_space(3))) unsigned int*)(unsigned long long)l,
      16, 0, 0);
}
__device__ inline unsigned q4(float a, float b, float c, float d, float mult){
  int qa = (int)fmaxf(-127.f, fminf(127.f, rintf(a*mult)));
  int qb = (int)fmaxf(-127.f, fminf(127.f, rintf(b*mult)));
  int qc = (int)fmaxf(-127.f, fminf(127.f, rintf(c*mult)));
  int qd = (int)fmaxf(-127.f, fminf(127.f, rintf(d*mult)));
  return (qa & 0xff) | ((qb & 0xff) << 8) | ((qc & 0xff) << 16) | ((qd & 0xff) << 24);
}

// stats != nullptr: also zero m0u/cnt (4096 contiguous u32) -- saves a launch.
__global__ void cvt_i8(const float* __restrict__ src, signed char* __restrict__ dst,
                       long nsrc, long ndst, float mult, unsigned* __restrict__ stats){
  long gid = (long)blockIdx.x * blockDim.x + threadIdx.x;
  if (stats && gid < 2*B_ROWS) stats[gid] = 0u;          // 0 == encf(-huge)
  long i = gid * 16;
  if (i >= ndst) return;
  uint4 o;
  if (i < nsrc){
    const float4* p = (const float4*)(src + i);
    float4 a = p[0], b = p[1], c = p[2], d = p[3];
    o.x = q4(a.x, a.y, a.z, a.w, mult);
    o.y = q4(b.x, b.y, b.z, b.w, mult);
    o.z = q4(c.x, c.y, c.z, c.w, mult);
    o.w = q4(d.x, d.y, d.z, d.w, mult);
  } else { o.x = o.y = o.z = o.w = 0u; }                 // zero pad rows >= NTOT
  *(uint4*)(dst + i) = o;
}

// BM=256 x BN=128, BK=64, 8 waves (4x2, 64x64 each), 3 tile-buffers (72 KB).
// Buffer layout (24 KB): A [256][64] at 0, B [128][64] at 16384.
// Staging per tile per lane: 3 llds16 (A rows 0-127, A rows 128-255, B).
// Per K-tile t: STAGE(t+2), 8 ds_read_b128 (plain C++ -> compiler's own fine
// lgkmcnt), 16 MFMA, then {vmcnt(3) counted; s_barrier} once per tile.
// Hazards as R4 (passed): end-of-(t-1) barrier implies all waves' t-1 reads
// drained (MFMA register deps force lgkm wait) before STAGE(t+2) overwrites
// buf((t-1)%3); per-wave vmcnt(3)+barrier at end of t ensures all waves'
// tile-(t+1) loads landed.
// Swizzle (R1-verified, conflicts=0): chunk slot c of row r stored at
// c ^ ((r>>1)&3); global source carries the inverse (global_load_lds is linear).
// MODE 0: prepass (per-row max -> atomicMax m0u). MODE 1: collect candidates.
template<int MODE>
__launch_bounds__(512, 4)
__global__ void gemm_tile(const signed char* __restrict__ A,   // [2048][512] i8 (quant 8*x)
                          const signed char* __restrict__ Bm,  // [100096][512] i8 (quant M)
                          unsigned* __restrict__ m0u,
                          unsigned* __restrict__ cnt,
                          int* __restrict__ cand,
                          float dq,                            // dequant scale sA*sM
                          int cpx){                            // grid chunk per XCD
  extern __shared__ signed char smem[];                  // 3 * 24576 bytes
  __shared__ float tt[256];

  // XCD-chunked bijective swizzle (grid = 8*cpx): XCD c (= bid%8) owns work
  // ids [c*cpx, (c+1)*cpx). qblk cycles fastest -> each B tile (nblk) is
  // consumed by 8 near-concurrent blocks on the same XCD -> L2-reused 8x;
  // A (1 MB total) is fully L2-resident.
  const int bid = blockIdx.x;
  const int w    = (bid & 7) * cpx + (bid >> 3);
  const int qblk = w & 7, nblk = w >> 3;

  const int tid  = threadIdx.x;
  const int lane = tid & 63, wave = tid >> 6;
  const int wr = wave >> 1, wc = wave & 1;               // 4x2 waves, 64x64 each
  const int quad = lane >> 4, l15 = lane & 15;

  if (MODE == 1 && tid < 256) tt[tid] = decf(m0u[qblk*256 + tid]) - MARGIN;

  // ---- staging geometry (per lane; constant across K-tiles) ----
  // Round r covers 128 rows: row = r*128 + wave*16 + lane/4; chunk p = lane&3;
  // source chunk = p ^ ((row>>1)&3) = p ^ ((lane>>3)&3) (r*64, w*8 drop mod 4).
  const int srow = wave*16 + (lane >> 2);
  const int sc   = (lane & 3) ^ ((lane >> 3) & 3);
  const signed char* gA0 = A  + (size_t)(qblk*256 + srow)*DDIM + sc*16;
  const signed char* gA1 = gA0 + (size_t)128*DDIM;
  const signed char* gB  = Bm + (size_t)(nblk*128 + srow)*DDIM + sc*16;

  // ---- fragment read offsets (within a 24 KB tile buffer) ----
  // A frag row r = wr*64 + i*16 + l15 -> read slot quad ^ ((r>>1)&3) =
  // quad ^ ((l15>>1)&3) (wr*32, i*8 drop out mod 4). B symmetric.
  const int swz = (quad ^ ((l15 >> 1) & 3)) << 4;
  int offA[4], offB[4];
  #pragma unroll
  for (int i = 0; i < 4; i++) offA[i] = (wr*64 + i*16 + l15)*64 + swz;
  #pragma unroll
  for (int j = 0; j < 4; j++) offB[j] = 16384 + (wc*64 + j*16 + l15)*64 + swz;

  i32x4 acc[4][4] = {};

  auto STAGE = [&](int t){                               // 3 llds16 per lane
    signed char* lb = smem + (t % 3) * 24576;
    const size_t o = (size_t)t * 64;
    llds16(gA0 + o, lb +         wave*1024);             // A rows 0..127
    llds16(gA1 + o, lb +  8192 + wave*1024);             // A rows 128..255
    llds16(gB  + o, lb + 16384 + wave*1024);             // B rows 0..127
  };

  // ---- prologue: stage tiles 0,1; wait tile 0 (3 newest = tile 1); sync ----
  STAGE(0); STAGE(1);
  VMCNT(3); BARR();

  #pragma unroll
  for (int t = 0; t < 8; ++t){                           // 512/64 = 8 K-tiles
    const signed char* bb = smem + (t % 3) * 24576;
    if (t + 2 < 8) STAGE(t + 2);                         // issue before compute
    i32x4 af[4], bf[4];
    #pragma unroll
    for (int j = 0; j < 4; j++) bf[j] = *(const i32x4*)(bb + offB[j]);
    #pragma unroll
    for (int i = 0; i < 4; i++) af[i] = *(const i32x4*)(bb + offA[i]);
    __builtin_amdgcn_s_setprio(1);
    #pragma unroll
    for (int i = 0; i < 4; i++)
      #pragma unroll
      for (int j = 0; j < 4; j++)
        acc[i][j] = __builtin_amdgcn_mfma_i32_16x16x64_i8(af[i], bf[j], acc[i][j], 0, 0, 0);
    __builtin_amdgcn_s_setprio(0);
    if (t < 7){
      if (t < 6) { VMCNT(3); } else { VMCNT(0); }        // t+1 landed (tail: drain)
      BARR();
    }
  }

  // C/D layout (shape-determined, m89/m121-verified): col = lane&15, row = quad*4 + reg
  if (MODE == 0){
    #pragma unroll
    for (int i = 0; i < 4; i++){
      #pragma unroll
      for (int r = 0; r < 4; r++){
        float v = fmaxf(fmaxf((float)acc[i][0][r], (float)acc[i][1][r]),
                        fmaxf((float)acc[i][2][r], (float)acc[i][3][r])) * dq;
        #pragma unroll
        for (int m = 1; m < 16; m <<= 1) v = fmaxf(v, __shfl_xor(v, m));
        if (l15 == 0){
          int row = qblk*256 + wr*64 + i*16 + quad*4 + r;
          atomicMax(&m0u[row], encf(v));
        }
      }
    }
  } else {
    const int nbase = nblk*128 + wc*64 + l15;
    #pragma unroll
    for (int i = 0; i < 4; i++){
      #pragma unroll
      for (int r = 0; r < 4; r++){
        const int lrow = wr*64 + i*16 + quad*4 + r;
        const float th = tt[lrow];
        #pragma unroll
        for (int j = 0; j < 4; j++){
          float v = (float)acc[i][j][r] * dq;
          int n = nbase + j*16;
          if (v > th && n < NTOT){                       // rare
            int q = qblk*256 + lrow;
            unsigned pos = atomicAdd(&cnt[q], 1u);
            if (pos < CAP) cand[(size_t)q*CAP + pos] = n;
          }
        }
      }
    }
  }
}

__global__ void finalize_row(const float* __restrict__ xin, const float* __restrict__ M,
                             const int* __restrict__ cand, const unsigned* __restrict__ cnt,
                             float* __restrict__ xout){
  __shared__ float xs[DDIM];
  __shared__ float lc[CAP];
  __shared__ int   sv[SCAP];
  __shared__ float mred[4];
  __shared__ int   ns;
  const int q = blockIdx.x, tid = threadIdx.x;
  const int wave = tid >> 6, lane = tid & 63;
  xs[tid]       = xin[(size_t)q*DDIM + tid];
  xs[tid + 256] = xin[(size_t)q*DDIM + 256 + tid];
  if (tid == 0) ns = 0;
  const unsigned cq = cnt[q];
  const int c0 = (int)(cq < (unsigned)CAP ? cq : (unsigned)CAP);
  __syncthreads();

  // Phase 1: exact fp32 logits for candidates (one wave per candidate)
  for (int c = wave; c < c0; c += 4){
    const float* Mr = M + (size_t)cand[(size_t)q*CAP + c]*DDIM;
    float s = 0.f;
    #pragma unroll
    for (int k = 0; k < 8; k++) s += xs[lane + 64*k] * Mr[lane + 64*k];
    #pragma unroll
    for (int o = 32; o; o >>= 1) s += __shfl_xor(s, o);
    if (lane == 0) lc[c] = 8.0f * s;
  }
  __syncthreads();

  // Phase 2: parallel max over candidates
  float m = -3.0e38f;
  for (int c = tid; c < c0; c += 256) m = fmaxf(m, lc[c]);
  #pragma unroll
  for (int o = 32; o; o >>= 1) m = fmaxf(m, __shfl_xor(m, o));
  if (lane == 0) mred[wave] = m;
  __syncthreads();
  m = fmaxf(fmaxf(mred[0], mred[1]), fmaxf(mred[2], mred[3]));

  // Phase 3: compact survivors (weight >= e^-WCUT; dropped tail < 7e-4 abs out)
  for (int c = tid; c < c0; c += 256){
    if (lc[c] > m - WCUT){
      int p = atomicAdd(&ns, 1);
      if (p < SCAP) sv[p] = c;
    }
  }
  __syncthreads();
  const int nsv = ns < SCAP ? ns : SCAP;

  // Phase 4: weighted gather over survivors only (typical 1-3)
  float Z = 0.f, a0 = 0.f, a1 = 0.f;
  for (int i = 0; i < nsv; i++){
    const int c = sv[i];
    const float w = expf(lc[c] - m);
    const float* Mr = M + (size_t)cand[(size_t)q*CAP + c]*DDIM;
    Z  += w;
    a0 += w * Mr[tid];
    a1 += w * Mr[tid + 256];
  }
  xout[(size_t)q*DDIM + tid]       = 1.f/(1.f + expf(-a0/Z));
  xout[(size_t)q*DDIM + tid + 256] = 1.f/(1.f + expf(-a1/Z));
}

extern "C" void kernel_launch(void* const* d_in, const int* in_sizes, int n_in,
                              void* d_out, int out_size, void* d_ws, size_t ws_size,
                              hipStream_t stream){
  const float* query = (const float*)d_in[0];
  const float* M     = (const float*)d_in[1];
  float* out = (float*)d_out;
  // steps (d_in[2]) is fixed at 2 for this problem; hardcoded below.

  char* w = (char*)d_ws;
  size_t off = 0;
  signed char* Bq   = (signed char*)(w + off); off += (size_t)NPAD*DDIM;     // 51.2 MB
  signed char* Aq   = (signed char*)(w + off); off += (size_t)B_ROWS*DDIM;   // 1 MB
  float*       xbuf = (float*)(w + off);       off += (size_t)B_ROWS*DDIM*4; // 4 MB
  unsigned*    m0u  = (unsigned*)(w + off);    off += (size_t)B_ROWS*4;
  unsigned*    cnt  = (unsigned*)(w + off);    off += (size_t)B_ROWS*4;      // contiguous after m0u
  int*         cand = (int*)(w + off);         off += (size_t)B_ROWS*CAP*4;  // 16.8 MB
  if (ws_size < off) return;

  // dynamic LDS 72 KB (host-side attr; graph-capture-safe, idempotent)
  hipFuncSetAttribute((const void*)gemm_tile<0>,
                      hipFuncAttributeMaxDynamicSharedMemorySize, 3*24576);
  hipFuncSetAttribute((const void*)gemm_tile<1>,
                      hipFuncAttributeMaxDynamicSharedMemorySize, 3*24576);

  // M quant: clip 4 sigma (N(0,1) entries), step 4/127
  const float MCLIP = 4.0f;
  cvt_i8<<<(long)NPAD*DDIM/16/256, 256, 0, stream>>>(M, Bq, (long)NTOT*DDIM, (long)NPAD*DDIM,
                                                     127.0f/MCLIP, nullptr);

  for (int step = 0; step < 2; ++step){
    const float* x = step ? (const float*)xbuf : query;
    float*       y = step ? out : xbuf;
    // A = 8*x quant: step0 x~N(0,1) -> clip |8x|<=40; step1 x=sigmoid in (0,1) -> |8x|<=8
    const float ACLIP = step ? 8.0f : 40.0f;
    const float multA = 8.0f * 127.0f / ACLIP;
    const float dq    = (ACLIP/127.0f) * (MCLIP/127.0f);
    // A-quant + zero m0u/cnt (m0u,cnt contiguous in ws) in one launch
    cvt_i8<<<(long)B_ROWS*DDIM/16/256, 256, 0, stream>>>(x, Aq, (long)B_ROWS*DDIM,
                                                         (long)B_ROWS*DDIM, multA, m0u);
    gemm_tile<0><<<8*PT, 512, 3*24576, stream>>>(Aq, Bq, m0u, cnt, cand, dq, PT);
    gemm_tile<1><<<8*NB, 512, 3*24576, stream>>>(Aq, Bq, m0u, cnt, cand, dq, NB);
    finalize_row<<<B_ROWS, 256, 0, stream>>>(x, M, cand, cnt, y);
  }
}